// Round 1
// baseline (629.014 us; speedup 1.0000x reference)
//
#include <hip/hip_runtime.h>

#define BN_EPS 1e-5f

// ---------------------------------------------------------------------------
// Build CSR offsets from sorted dst. off[n] = first edge index with dst >= n,
// n in [0, N]. Node n's incoming edges are [off[n], off[n+1]).
// ---------------------------------------------------------------------------
__global__ __launch_bounds__(256) void build_off_k(const int* __restrict__ dst,
                                                   int* __restrict__ off, int E, int N) {
    int i = blockIdx.x * 256 + threadIdx.x;
    if (i > E) return;
    int cur  = (i < E) ? dst[i] : N;
    int prev = (i == 0) ? -1 : dst[i - 1];
    for (int n = prev + 1; n <= cur; ++n) off[n] = i;
}

__global__ void zero_k(float* p, int n) {
    int i = blockIdx.x * blockDim.x + threadIdx.x;
    if (i < n) p[i] = 0.f;
}

// ---------------------------------------------------------------------------
// fp32 GEMM: M[N x OUTC] = X[N x 128] @ W[128 x OUTC]
// Block: 256 threads, 64 rows per block. W + X tile staged in LDS.
// ---------------------------------------------------------------------------
template <int OUTC>
__global__ __launch_bounds__(256) void gemm_k(const float* __restrict__ X,
                                              const float* __restrict__ W,
                                              float* __restrict__ M, int N) {
    __shared__ float sX[64][132];       // pad to 132 floats: keeps float4 16B-aligned
    __shared__ float sW[128][OUTC];
    const int tid  = threadIdx.x;
    const int row0 = blockIdx.x * 64;

    constexpr int WQ = 128 * OUTC / 4;
    const float4* W4 = (const float4*)W;
    #pragma unroll
    for (int q = tid; q < WQ; q += 256) {
        int k  = q / (OUTC / 4);
        int c4 = q % (OUTC / 4);
        *(float4*)&sW[k][c4 * 4] = W4[q];
    }
    const float4* X4 = (const float4*)X;
    #pragma unroll
    for (int q = tid; q < 64 * 32; q += 256) {
        int r = q >> 5, k4 = q & 31;
        int gr = row0 + r;
        float4 v = make_float4(0.f, 0.f, 0.f, 0.f);
        if (gr < N) v = X4[gr * 32 + k4];
        *(float4*)&sX[r][k4 * 4] = v;
    }
    __syncthreads();

    const int ty = tid >> 4, tx = tid & 15;   // 16x16 thread grid
    constexpr int CPT = OUTC / 16;            // cols per thread (8 or 4)
    float acc[4][CPT];
    #pragma unroll
    for (int i = 0; i < 4; ++i)
        #pragma unroll
        for (int j = 0; j < CPT; ++j) acc[i][j] = 0.f;

    #pragma unroll 8
    for (int k = 0; k < 128; ++k) {
        float a[4], b[CPT];
        #pragma unroll
        for (int i = 0; i < 4; ++i) a[i] = sX[ty * 4 + i][k];
        #pragma unroll
        for (int j = 0; j < CPT; ++j) b[j] = sW[k][tx * CPT + j];
        #pragma unroll
        for (int i = 0; i < 4; ++i)
            #pragma unroll
            for (int j = 0; j < CPT; ++j) acc[i][j] = fmaf(a[i], b[j], acc[i][j]);
    }

    #pragma unroll
    for (int i = 0; i < 4; ++i) {
        int gr = row0 + ty * 4 + i;
        if (gr < N) {
            #pragma unroll
            for (int j = 0; j < CPT; j += 4) {
                float4 v = make_float4(acc[i][j], acc[i][j + 1], acc[i][j + 2], acc[i][j + 3]);
                *(float4*)&M[gr * OUTC + tx * CPT + j] = v;
            }
        }
    }
}

// ---------------------------------------------------------------------------
// Segment-sum aggregation (dst sorted -> CSR ranges, no atomics).
// One wave per node; lane covers 2 channels (C=128) or 1 channel (C=64).
// H[n][:] = sum_{e in [off[n],off[n+1])} M[src[e]][:] + bias
// ---------------------------------------------------------------------------
template <int C>
__global__ __launch_bounds__(256) void agg_k(const float* __restrict__ M,
                                             const int* __restrict__ src,
                                             const int* __restrict__ off,
                                             const float* __restrict__ bias,
                                             float* __restrict__ H, int N) {
    const int lane = threadIdx.x & 63;
    const int node = blockIdx.x * 4 + (threadIdx.x >> 6);
    if (node >= N) return;
    const int e0 = off[node], e1 = off[node + 1];

    if constexpr (C == 128) {
        const int c2 = lane * 2;
        float2 acc = make_float2(0.f, 0.f);
        for (int base = e0; base < e1; base += 64) {
            int e = base + lane;
            int s = (e < e1) ? src[e] : 0;
            int cnt = min(64, e1 - base);
            int i = 0;
            for (; i + 4 <= cnt; i += 4) {
                int s0 = __shfl(s, i),     s1 = __shfl(s, i + 1);
                int s2 = __shfl(s, i + 2), s3 = __shfl(s, i + 3);
                float2 v0 = *(const float2*)&M[s0 * 128 + c2];
                float2 v1 = *(const float2*)&M[s1 * 128 + c2];
                float2 v2 = *(const float2*)&M[s2 * 128 + c2];
                float2 v3 = *(const float2*)&M[s3 * 128 + c2];
                acc.x += (v0.x + v1.x) + (v2.x + v3.x);
                acc.y += (v0.y + v1.y) + (v2.y + v3.y);
            }
            for (; i < cnt; ++i) {
                int si = __shfl(s, i);
                float2 v = *(const float2*)&M[si * 128 + c2];
                acc.x += v.x; acc.y += v.y;
            }
        }
        float2 bv = *(const float2*)&bias[c2];
        *(float2*)&H[node * 128 + c2] = make_float2(acc.x + bv.x, acc.y + bv.y);
    } else {
        float acc = 0.f;
        for (int base = e0; base < e1; base += 64) {
            int e = base + lane;
            int s = (e < e1) ? src[e] : 0;
            int cnt = min(64, e1 - base);
            int i = 0;
            for (; i + 4 <= cnt; i += 4) {
                int s0 = __shfl(s, i),     s1 = __shfl(s, i + 1);
                int s2 = __shfl(s, i + 2), s3 = __shfl(s, i + 3);
                float v0 = M[s0 * 64 + lane], v1 = M[s1 * 64 + lane];
                float v2 = M[s2 * 64 + lane], v3 = M[s3 * 64 + lane];
                acc += (v0 + v1) + (v2 + v3);
            }
            for (; i < cnt; ++i) {
                int si = __shfl(s, i);
                acc += M[si * 64 + lane];
            }
        }
        H[node * 64 + lane] = acc + bias[lane];
    }
}

// ---------------------------------------------------------------------------
// Column sums / sum-of-squares for BN (128 channels). Per-block partials in
// registers+LDS, then one atomicAdd per channel per block (512 blocks).
// ---------------------------------------------------------------------------
__global__ __launch_bounds__(256) void stats_k(const float* __restrict__ H,
                                               float* __restrict__ stats, int N) {
    const int c = threadIdx.x & 127;
    const int half = threadIdx.x >> 7;
    float sum = 0.f, sq = 0.f;
    for (int r = blockIdx.x * 2 + half; r < N; r += gridDim.x * 2) {
        float v = H[r * 128 + c];
        sum += v; sq = fmaf(v, v, sq);
    }
    __shared__ float sS[128], sQ[128];
    if (half) { sS[c] = sum; sQ[c] = sq; }
    __syncthreads();
    if (!half) {
        atomicAdd(&stats[c], sum + sS[c]);
        atomicAdd(&stats[128 + c], sq + sQ[c]);
    }
}

// stats -> per-channel scale/shift:  out = h*sc + sh  ==  (h-mu)*rsqrt(var+eps)*g + beta
__global__ void bnfin_k(const float* __restrict__ stats, const float* __restrict__ gamma,
                        const float* __restrict__ beta, float* __restrict__ ss, float invN) {
    int c = threadIdx.x;   // 128 threads
    float mu  = stats[c] * invN;
    float var = fmaf(-mu, mu, stats[128 + c] * invN);
    float sc  = gamma[c] * rsqrtf(var + BN_EPS);
    ss[c]       = sc;
    ss[128 + c] = fmaf(-mu, sc, beta[c]);
}

// Fused BN-apply + residual + ReLU, elementwise float4, safe in-place on H.
__global__ __launch_bounds__(256) void apply_k(const float* H,
                                               const float* __restrict__ R,
                                               const float* __restrict__ ss,
                                               float* Xn, int n4) {
    int i = blockIdx.x * 256 + threadIdx.x;
    if (i >= n4) return;
    int c4 = (i & 31) << 2;   // 128 ch = 32 float4 per row
    float4 h = ((const float4*)H)[i];
    float4 r = ((const float4*)R)[i];
    float4 o;
    o.x = fmaxf(fmaf(h.x, ss[c4 + 0], ss[128 + c4 + 0]) + r.x, 0.f);
    o.y = fmaxf(fmaf(h.y, ss[c4 + 1], ss[128 + c4 + 1]) + r.y, 0.f);
    o.z = fmaxf(fmaf(h.z, ss[c4 + 2], ss[128 + c4 + 2]) + r.z, 0.f);
    o.w = fmaxf(fmaf(h.w, ss[c4 + 3], ss[128 + c4 + 3]) + r.w, 0.f);
    ((float4*)Xn)[i] = o;
}

// ---------------------------------------------------------------------------
extern "C" void kernel_launch(void* const* d_in, const int* in_sizes, int n_in,
                              void* d_out, int out_size, void* d_ws, size_t ws_size,
                              hipStream_t stream) {
    const float* x   = (const float*)d_in[0];
    const int*   src = (const int*)d_in[1];
    const int*   dst = (const int*)d_in[2];
    const float* W0  = (const float*)d_in[3];
    const float* b0  = (const float*)d_in[4];
    const float* W1  = (const float*)d_in[5];
    const float* b1  = (const float*)d_in[6];
    const float* W2  = (const float*)d_in[7];
    const float* b2  = (const float*)d_in[8];
    const float* g0  = (const float*)d_in[9];
    const float* be0 = (const float*)d_in[10];
    const float* g1  = (const float*)d_in[11];
    const float* be1 = (const float*)d_in[12];
    float* out = (float*)d_out;

    const int N = in_sizes[0] / 128;
    const int E = in_sizes[1];

    // workspace layout: 3 ping-pong N x 128 fp32 buffers + offsets + stats
    char*  ws   = (char*)d_ws;
    size_t bufB = (size_t)N * 128 * sizeof(float);
    float* A  = (float*)(ws);
    float* B  = (float*)(ws + bufB);
    float* Cb = (float*)(ws + 2 * bufB);
    size_t p  = 3 * bufB;
    int*   off = (int*)(ws + p);
    p += ((size_t)(N + 1) * sizeof(int) + 255) & ~(size_t)255;
    float* stats0 = (float*)(ws + p); p += 1024;   // 256 floats
    float* stats1 = (float*)(ws + p); p += 1024;
    float* ss     = (float*)(ws + p); p += 1024;

    const dim3 blk(256);
    const int gGemm  = (N + 63) / 64;
    const int gAgg   = (N + 3) / 4;
    const int gApply = (N * 32 + 255) / 256;
    const float invN = 1.f / (float)N;

    zero_k<<<2, blk, 0, stream>>>(stats0, 512);                  // stats0+stats1 contiguous
    build_off_k<<<(E + 256) / 256, blk, 0, stream>>>(dst, off, E, N);

    // ---- layer 0: conv -> BN -> +x -> ReLU ----
    gemm_k<128><<<gGemm, blk, 0, stream>>>(x, W0, A, N);
    agg_k<128><<<gAgg, blk, 0, stream>>>(A, src, off, b0, B, N);
    stats_k<<<512, blk, 0, stream>>>(B, stats0, N);
    bnfin_k<<<1, 128, 0, stream>>>(stats0, g0, be0, ss, invN);
    apply_k<<<gApply, blk, 0, stream>>>(B, x, ss, B, N * 32);    // x1 = B (in-place)

    // ---- layer 1 ----
    gemm_k<128><<<gGemm, blk, 0, stream>>>(B, W1, A, N);
    agg_k<128><<<gAgg, blk, 0, stream>>>(A, src, off, b1, Cb, N);
    stats_k<<<512, blk, 0, stream>>>(Cb, stats1, N);
    bnfin_k<<<1, 128, 0, stream>>>(stats1, g1, be1, ss, invN);
    apply_k<<<gApply, blk, 0, stream>>>(Cb, B, ss, Cb, N * 32);  // x2 = Cb (in-place)

    // ---- final conv ----
    gemm_k<64><<<gGemm, blk, 0, stream>>>(Cb, W2, A, N);
    agg_k<64><<<gAgg, blk, 0, stream>>>(A, src, off, b2, out, N);
}

// Round 2
// 482.988 us; speedup vs baseline: 1.3023x; 1.3023x over previous
//
#include <hip/hip_runtime.h>

#define BN_EPS 1e-5f

typedef __attribute__((ext_vector_type(8))) short bf16x8;
typedef __attribute__((ext_vector_type(4))) float f32x4;

__device__ __forceinline__ short f2bf(float f) {
    union { float f; unsigned u; } v; v.f = f;
    unsigned r = (v.u + 0x7fffu + ((v.u >> 16) & 1u)) >> 16;
    return (short)r;
}

// ---------------------------------------------------------------------------
// Build CSR offsets from sorted dst. off[n] = first edge index with dst >= n.
// ---------------------------------------------------------------------------
__global__ __launch_bounds__(256) void build_off_k(const int* __restrict__ dst,
                                                   int* __restrict__ off, int E, int N) {
    int i = blockIdx.x * 256 + threadIdx.x;
    if (i > E) return;
    int cur  = (i < E) ? dst[i] : N;
    int prev = (i == 0) ? -1 : dst[i - 1];
    for (int n = prev + 1; n <= cur; ++n) off[n] = i;
}

__global__ void zero_k(float* p, int n) {
    int i = blockIdx.x * blockDim.x + threadIdx.x;
    if (i < n) p[i] = 0.f;
}

// Transpose + convert weights: Wt[c][k] = bf16(W[k][c]).  K*C elements, tiny.
__global__ __launch_bounds__(256) void wtrans_k(const float* __restrict__ W,
                                                short* __restrict__ Wt, int K, int C) {
    int i = blockIdx.x * 256 + threadIdx.x;
    if (i >= K * C) return;
    int c = i / K, k = i % K;
    Wt[i] = f2bf(W[k * C + c]);
}

// ---------------------------------------------------------------------------
// MFMA GEMM: M[N x OUTC] (fp32) = X[N x 128] (fp32, cvt->bf16 in-reg) @ W
// W given pre-transposed bf16: Wt[OUTC][128].
// Block = 256 thr (4 waves); wave w -> rows [blk*128 + w*32, +32), all OUTC cols.
// mfma_f32_16x16x32_bf16: A row=lane&15,k=(lane>>4)*8+j ; B col=lane&15 ;
// C/D col=lane&15,row=(lane>>4)*4+reg  (m89-verified).
// ---------------------------------------------------------------------------
template <int OUTC>
__global__ __launch_bounds__(256) void mgemm_k(const float* __restrict__ X,
                                               const short* __restrict__ Wt,
                                               float* __restrict__ M, int N) {
    constexpr int NR = OUTC / 16;            // 8 or 4 col-frags per wave
    __shared__ short sW[OUTC][136];          // pad 8 bf16 -> 272B stride (2-way, free)

    const int tid = threadIdx.x;
    // stage Wt (OUTC*128 bf16) as 16B chunks
    for (int q = tid; q < OUTC * 16; q += 256) {
        int r = q >> 4, s = q & 15;
        *(int4*)&sW[r][s * 8] = ((const int4*)Wt)[q];
    }
    __syncthreads();

    const int wave = tid >> 6, lane = tid & 63;
    const int lr = lane & 15, lg = lane >> 4;
    const int row0 = blockIdx.x * 128 + wave * 32;

    f32x4 acc[2][NR];
    #pragma unroll
    for (int m = 0; m < 2; ++m)
        #pragma unroll
        for (int n = 0; n < NR; ++n) acc[m][n] = (f32x4){0.f, 0.f, 0.f, 0.f};

    #pragma unroll
    for (int kk = 0; kk < 4; ++kk) {
        bf16x8 a[2];
        #pragma unroll
        for (int m = 0; m < 2; ++m) {
            int row = row0 + m * 16 + lr;
            float4 x0 = make_float4(0.f, 0.f, 0.f, 0.f), x1 = x0;
            if (row < N) {
                const float4* p = (const float4*)&X[(size_t)row * 128 + kk * 32 + lg * 8];
                x0 = p[0]; x1 = p[1];
            }
            a[m][0] = f2bf(x0.x); a[m][1] = f2bf(x0.y);
            a[m][2] = f2bf(x0.z); a[m][3] = f2bf(x0.w);
            a[m][4] = f2bf(x1.x); a[m][5] = f2bf(x1.y);
            a[m][6] = f2bf(x1.z); a[m][7] = f2bf(x1.w);
        }
        #pragma unroll
        for (int n = 0; n < NR; ++n) {
            bf16x8 b = *(const bf16x8*)&sW[n * 16 + lr][kk * 32 + lg * 8];
            acc[0][n] = __builtin_amdgcn_mfma_f32_16x16x32_bf16(a[0], b, acc[0][n], 0, 0, 0);
            acc[1][n] = __builtin_amdgcn_mfma_f32_16x16x32_bf16(a[1], b, acc[1][n], 0, 0, 0);
        }
    }

    #pragma unroll
    for (int m = 0; m < 2; ++m)
        #pragma unroll
        for (int r = 0; r < 4; ++r) {
            int row = row0 + m * 16 + lg * 4 + r;
            if (row < N) {
                #pragma unroll
                for (int n = 0; n < NR; ++n)
                    M[(size_t)row * OUTC + n * 16 + lr] = acc[m][n][r];
            }
        }
}

// ---------------------------------------------------------------------------
// Segment-sum aggregation (dst sorted -> CSR, no atomics). One wave per node.
// ---------------------------------------------------------------------------
template <int C>
__global__ __launch_bounds__(256) void agg_k(const float* __restrict__ M,
                                             const int* __restrict__ src,
                                             const int* __restrict__ off,
                                             const float* __restrict__ bias,
                                             float* __restrict__ H, int N) {
    const int lane = threadIdx.x & 63;
    const int node = blockIdx.x * 4 + (threadIdx.x >> 6);
    if (node >= N) return;
    const int e0 = off[node], e1 = off[node + 1];

    if constexpr (C == 128) {
        const int c2 = lane * 2;
        float2 acc = make_float2(0.f, 0.f);
        for (int base = e0; base < e1; base += 64) {
            int e = base + lane;
            int s = (e < e1) ? src[e] : 0;
            int cnt = min(64, e1 - base);
            int i = 0;
            for (; i + 4 <= cnt; i += 4) {
                int s0 = __shfl(s, i),     s1 = __shfl(s, i + 1);
                int s2 = __shfl(s, i + 2), s3 = __shfl(s, i + 3);
                float2 v0 = *(const float2*)&M[s0 * 128 + c2];
                float2 v1 = *(const float2*)&M[s1 * 128 + c2];
                float2 v2 = *(const float2*)&M[s2 * 128 + c2];
                float2 v3 = *(const float2*)&M[s3 * 128 + c2];
                acc.x += (v0.x + v1.x) + (v2.x + v3.x);
                acc.y += (v0.y + v1.y) + (v2.y + v3.y);
            }
            for (; i < cnt; ++i) {
                int si = __shfl(s, i);
                float2 v = *(const float2*)&M[si * 128 + c2];
                acc.x += v.x; acc.y += v.y;
            }
        }
        float2 bv = *(const float2*)&bias[c2];
        *(float2*)&H[node * 128 + c2] = make_float2(acc.x + bv.x, acc.y + bv.y);
    } else {
        float acc = 0.f;
        for (int base = e0; base < e1; base += 64) {
            int e = base + lane;
            int s = (e < e1) ? src[e] : 0;
            int cnt = min(64, e1 - base);
            int i = 0;
            for (; i + 4 <= cnt; i += 4) {
                int s0 = __shfl(s, i),     s1 = __shfl(s, i + 1);
                int s2 = __shfl(s, i + 2), s3 = __shfl(s, i + 3);
                float v0 = M[s0 * 64 + lane], v1 = M[s1 * 64 + lane];
                float v2 = M[s2 * 64 + lane], v3 = M[s3 * 64 + lane];
                acc += (v0 + v1) + (v2 + v3);
            }
            for (; i < cnt; ++i) {
                int si = __shfl(s, i);
                acc += M[si * 64 + lane];
            }
        }
        H[node * 64 + lane] = acc + bias[lane];
    }
}

// ---------------------------------------------------------------------------
// BN column stats (sum, sumsq) with per-block partials + atomics.
// ---------------------------------------------------------------------------
__global__ __launch_bounds__(256) void stats_k(const float* __restrict__ H,
                                               float* __restrict__ stats, int N) {
    const int c = threadIdx.x & 127;
    const int half = threadIdx.x >> 7;
    float sum = 0.f, sq = 0.f;
    for (int r = blockIdx.x * 2 + half; r < N; r += gridDim.x * 2) {
        float v = H[r * 128 + c];
        sum += v; sq = fmaf(v, v, sq);
    }
    __shared__ float sS[128], sQ[128];
    if (half) { sS[c] = sum; sQ[c] = sq; }
    __syncthreads();
    if (!half) {
        atomicAdd(&stats[c], sum + sS[c]);
        atomicAdd(&stats[128 + c], sq + sQ[c]);
    }
}

__global__ void bnfin_k(const float* __restrict__ stats, const float* __restrict__ gamma,
                        const float* __restrict__ beta, float* __restrict__ ss, float invN) {
    int c = threadIdx.x;   // 128 threads
    float mu  = stats[c] * invN;
    float var = fmaf(-mu, mu, stats[128 + c] * invN);
    float sc  = gamma[c] * rsqrtf(var + BN_EPS);
    ss[c]       = sc;
    ss[128 + c] = fmaf(-mu, sc, beta[c]);
}

// Fused BN-apply + residual + ReLU, elementwise float4, safe in-place.
__global__ __launch_bounds__(256) void apply_k(const float* H,
                                               const float* __restrict__ R,
                                               const float* __restrict__ ss,
                                               float* Xn, int n4) {
    int i = blockIdx.x * 256 + threadIdx.x;
    if (i >= n4) return;
    int c4 = (i & 31) << 2;
    float4 h = ((const float4*)H)[i];
    float4 r = ((const float4*)R)[i];
    float4 o;
    o.x = fmaxf(fmaf(h.x, ss[c4 + 0], ss[128 + c4 + 0]) + r.x, 0.f);
    o.y = fmaxf(fmaf(h.y, ss[c4 + 1], ss[128 + c4 + 1]) + r.y, 0.f);
    o.z = fmaxf(fmaf(h.z, ss[c4 + 2], ss[128 + c4 + 2]) + r.z, 0.f);
    o.w = fmaxf(fmaf(h.w, ss[c4 + 3], ss[128 + c4 + 3]) + r.w, 0.f);
    ((float4*)Xn)[i] = o;
}

// ---------------------------------------------------------------------------
extern "C" void kernel_launch(void* const* d_in, const int* in_sizes, int n_in,
                              void* d_out, int out_size, void* d_ws, size_t ws_size,
                              hipStream_t stream) {
    const float* x   = (const float*)d_in[0];
    const int*   src = (const int*)d_in[1];
    const int*   dst = (const int*)d_in[2];
    const float* W0  = (const float*)d_in[3];
    const float* b0  = (const float*)d_in[4];
    const float* W1  = (const float*)d_in[5];
    const float* b1  = (const float*)d_in[6];
    const float* W2  = (const float*)d_in[7];
    const float* b2  = (const float*)d_in[8];
    const float* g0  = (const float*)d_in[9];
    const float* be0 = (const float*)d_in[10];
    const float* g1  = (const float*)d_in[11];
    const float* be1 = (const float*)d_in[12];
    float* out = (float*)d_out;

    const int N = in_sizes[0] / 128;
    const int E = in_sizes[1];

    // workspace: 3 ping-pong N x 128 fp32 buffers + Wt bf16 + offsets + stats
    char*  ws   = (char*)d_ws;
    size_t bufB = (size_t)N * 128 * sizeof(float);
    float* A  = (float*)(ws);
    float* B  = (float*)(ws + bufB);
    float* Cb = (float*)(ws + 2 * bufB);
    size_t p  = 3 * bufB;
    int*   off = (int*)(ws + p);
    p += ((size_t)(N + 1) * sizeof(int) + 255) & ~(size_t)255;
    float* stats0 = (float*)(ws + p); p += 1024;
    float* stats1 = (float*)(ws + p); p += 1024;
    float* ss     = (float*)(ws + p); p += 1024;
    short* Wt0    = (short*)(ws + p); p += 128 * 128 * 2;
    short* Wt1    = (short*)(ws + p); p += 128 * 128 * 2;
    short* Wt2    = (short*)(ws + p); p += 128 * 64 * 2;

    const dim3 blk(256);
    const int gGemm  = (N + 127) / 128;
    const int gAgg   = (N + 3) / 4;
    const int gApply = (N * 32 + 255) / 256;
    const float invN = 1.f / (float)N;

    zero_k<<<2, blk, 0, stream>>>(stats0, 512);
    wtrans_k<<<64, blk, 0, stream>>>(W0, Wt0, 128, 128);
    wtrans_k<<<64, blk, 0, stream>>>(W1, Wt1, 128, 128);
    wtrans_k<<<32, blk, 0, stream>>>(W2, Wt2, 128, 64);
    build_off_k<<<(E + 256) / 256, blk, 0, stream>>>(dst, off, E, N);

    // ---- layer 0 ----
    mgemm_k<128><<<gGemm, blk, 0, stream>>>(x, Wt0, A, N);
    agg_k<128><<<gAgg, blk, 0, stream>>>(A, src, off, b0, B, N);
    stats_k<<<1024, blk, 0, stream>>>(B, stats0, N);
    bnfin_k<<<1, 128, 0, stream>>>(stats0, g0, be0, ss, invN);
    apply_k<<<gApply, blk, 0, stream>>>(B, x, ss, B, N * 32);

    // ---- layer 1 ----
    mgemm_k<128><<<gGemm, blk, 0, stream>>>(B, Wt1, A, N);
    agg_k<128><<<gAgg, blk, 0, stream>>>(A, src, off, b1, Cb, N);
    stats_k<<<1024, blk, 0, stream>>>(Cb, stats1, N);
    bnfin_k<<<1, 128, 0, stream>>>(stats1, g1, be1, ss, invN);
    apply_k<<<gApply, blk, 0, stream>>>(Cb, B, ss, Cb, N * 32);

    // ---- final conv ----
    mgemm_k<64><<<gGemm, blk, 0, stream>>>(Cb, Wt2, A, N);
    agg_k<64><<<gAgg, blk, 0, stream>>>(A, src, off, b2, out, N);
}

// Round 3
// 372.997 us; speedup vs baseline: 1.6864x; 1.2949x over previous
//
#include <hip/hip_runtime.h>

#define BN_EPS 1e-5f

typedef __attribute__((ext_vector_type(8))) short bf16x8;
typedef __attribute__((ext_vector_type(4))) float f32x4;

__device__ __forceinline__ short f2bf(float f) {
    union { float f; unsigned u; } v; v.f = f;
    unsigned r = (v.u + 0x7fffu + ((v.u >> 16) & 1u)) >> 16;
    return (short)r;
}
__device__ __forceinline__ float bflo(unsigned d) {
    union { unsigned u; float f; } v; v.u = d << 16; return v.f;
}
__device__ __forceinline__ float bfhi(unsigned d) {
    union { unsigned u; float f; } v; v.u = d & 0xffff0000u; return v.f;
}

// ---------------------------------------------------------------------------
// Build CSR offsets from sorted dst. off[n] = first edge index with dst >= n.
// ---------------------------------------------------------------------------
__global__ __launch_bounds__(256) void build_off_k(const int* __restrict__ dst,
                                                   int* __restrict__ off, int E, int N) {
    int i = blockIdx.x * 256 + threadIdx.x;
    if (i > E) return;
    int cur  = (i < E) ? dst[i] : N;
    int prev = (i == 0) ? -1 : dst[i - 1];
    for (int n = prev + 1; n <= cur; ++n) off[n] = i;
}

__global__ void zero_k(float* p, int n) {
    int i = blockIdx.x * blockDim.x + threadIdx.x;
    if (i < n) p[i] = 0.f;
}

// Transpose + convert weights: Wt[c][k] = bf16(W[k][c]).
__global__ __launch_bounds__(256) void wtrans_k(const float* __restrict__ W,
                                                short* __restrict__ Wt, int K, int C) {
    int i = blockIdx.x * 256 + threadIdx.x;
    if (i >= K * C) return;
    int c = i / K, k = i % K;
    Wt[i] = f2bf(W[k * C + c]);
}

// ---------------------------------------------------------------------------
// MFMA GEMM: M[N x OUTC] (bf16 out) = X[N x 128] (fp32, cvt->bf16 in-reg) @ W
// W pre-transposed bf16: Wt[OUTC][128]. Block = 256 thr (4 waves), 128 rows.
// mfma_f32_16x16x32_bf16 layouts per m89/m92-verified mapping.
// ---------------------------------------------------------------------------
template <int OUTC>
__global__ __launch_bounds__(256) void mgemm_k(const float* __restrict__ X,
                                               const short* __restrict__ Wt,
                                               short* __restrict__ M, int N) {
    constexpr int NR = OUTC / 16;
    __shared__ short sW[OUTC][136];          // 272B stride: 2-way conflict = free

    const int tid = threadIdx.x;
    for (int q = tid; q < OUTC * 16; q += 256) {
        int r = q >> 4, s = q & 15;
        *(int4*)&sW[r][s * 8] = ((const int4*)Wt)[q];
    }
    __syncthreads();

    const int wave = tid >> 6, lane = tid & 63;
    const int lr = lane & 15, lg = lane >> 4;
    const int row0 = blockIdx.x * 128 + wave * 32;

    f32x4 acc[2][NR];
    #pragma unroll
    for (int m = 0; m < 2; ++m)
        #pragma unroll
        for (int n = 0; n < NR; ++n) acc[m][n] = (f32x4){0.f, 0.f, 0.f, 0.f};

    #pragma unroll
    for (int kk = 0; kk < 4; ++kk) {
        bf16x8 a[2];
        #pragma unroll
        for (int m = 0; m < 2; ++m) {
            int row = row0 + m * 16 + lr;
            float4 x0 = make_float4(0.f, 0.f, 0.f, 0.f), x1 = x0;
            if (row < N) {
                const float4* p = (const float4*)&X[(size_t)row * 128 + kk * 32 + lg * 8];
                x0 = p[0]; x1 = p[1];
            }
            a[m][0] = f2bf(x0.x); a[m][1] = f2bf(x0.y);
            a[m][2] = f2bf(x0.z); a[m][3] = f2bf(x0.w);
            a[m][4] = f2bf(x1.x); a[m][5] = f2bf(x1.y);
            a[m][6] = f2bf(x1.z); a[m][7] = f2bf(x1.w);
        }
        #pragma unroll
        for (int n = 0; n < NR; ++n) {
            bf16x8 b = *(const bf16x8*)&sW[n * 16 + lr][kk * 32 + lg * 8];
            acc[0][n] = __builtin_amdgcn_mfma_f32_16x16x32_bf16(a[0], b, acc[0][n], 0, 0, 0);
            acc[1][n] = __builtin_amdgcn_mfma_f32_16x16x32_bf16(a[1], b, acc[1][n], 0, 0, 0);
        }
    }

    #pragma unroll
    for (int m = 0; m < 2; ++m)
        #pragma unroll
        for (int r = 0; r < 4; ++r) {
            int row = row0 + m * 16 + lg * 4 + r;
            if (row < N) {
                #pragma unroll
                for (int n = 0; n < NR; ++n)
                    M[(size_t)row * OUTC + n * 16 + lr] = f2bf(acc[m][n][r]);
            }
        }
}

// ---------------------------------------------------------------------------
// Segment-sum aggregation over bf16 M (dst sorted -> CSR, no atomics).
// One wave per node. C=128: lane gathers 1 dword (2 ch); C=64: 1 ushort.
// H fp32 = sum + bias.
// ---------------------------------------------------------------------------
template <int C>
__global__ __launch_bounds__(256) void agg_k(const short* __restrict__ M,
                                             const int* __restrict__ src,
                                             const int* __restrict__ off,
                                             const float* __restrict__ bias,
                                             float* __restrict__ H, int N) {
    const int lane = threadIdx.x & 63;
    const int node = blockIdx.x * 4 + (threadIdx.x >> 6);
    if (node >= N) return;
    const int e0 = off[node], e1 = off[node + 1];

    if constexpr (C == 128) {
        const unsigned* M32 = (const unsigned*)M;   // 64 dwords per row
        float2 acc = make_float2(0.f, 0.f);
        for (int base = e0; base < e1; base += 64) {
            int e = base + lane;
            int s = (e < e1) ? src[e] : 0;
            int cnt = min(64, e1 - base);
            int i = 0;
            for (; i + 4 <= cnt; i += 4) {
                int s0 = __shfl(s, i),     s1 = __shfl(s, i + 1);
                int s2 = __shfl(s, i + 2), s3 = __shfl(s, i + 3);
                unsigned d0 = M32[s0 * 64 + lane];
                unsigned d1 = M32[s1 * 64 + lane];
                unsigned d2 = M32[s2 * 64 + lane];
                unsigned d3 = M32[s3 * 64 + lane];
                acc.x += (bflo(d0) + bflo(d1)) + (bflo(d2) + bflo(d3));
                acc.y += (bfhi(d0) + bfhi(d1)) + (bfhi(d2) + bfhi(d3));
            }
            for (; i < cnt; ++i) {
                int si = __shfl(s, i);
                unsigned d = M32[si * 64 + lane];
                acc.x += bflo(d); acc.y += bfhi(d);
            }
        }
        float2 bv = *(const float2*)&bias[lane * 2];
        *(float2*)&H[node * 128 + lane * 2] = make_float2(acc.x + bv.x, acc.y + bv.y);
    } else {
        const unsigned short* M16 = (const unsigned short*)M;
        float acc = 0.f;
        for (int base = e0; base < e1; base += 64) {
            int e = base + lane;
            int s = (e < e1) ? src[e] : 0;
            int cnt = min(64, e1 - base);
            int i = 0;
            for (; i + 4 <= cnt; i += 4) {
                int s0 = __shfl(s, i),     s1 = __shfl(s, i + 1);
                int s2 = __shfl(s, i + 2), s3 = __shfl(s, i + 3);
                float v0 = bflo((unsigned)M16[s0 * 64 + lane] << 16 >> 16 | ((unsigned)M16[s0 * 64 + lane] << 16));
                // simpler: bits<<16
                v0 = bflo((unsigned)M16[s0 * 64 + lane]);
                float v1 = bflo((unsigned)M16[s1 * 64 + lane]);
                float v2 = bflo((unsigned)M16[s2 * 64 + lane]);
                float v3 = bflo((unsigned)M16[s3 * 64 + lane]);
                acc += (v0 + v1) + (v2 + v3);
            }
            for (; i < cnt; ++i) {
                int si = __shfl(s, i);
                acc += bflo((unsigned)M16[si * 64 + lane]);
            }
        }
        H[node * 64 + lane] = acc + bias[lane];
    }
}

// ---------------------------------------------------------------------------
// BN column stats (sum, sumsq) with per-block partials + atomics.
// ---------------------------------------------------------------------------
__global__ __launch_bounds__(256) void stats_k(const float* __restrict__ H,
                                               float* __restrict__ stats, int N) {
    const int c = threadIdx.x & 127;
    const int half = threadIdx.x >> 7;
    float sum = 0.f, sq = 0.f;
    for (int r = blockIdx.x * 2 + half; r < N; r += gridDim.x * 2) {
        float v = H[r * 128 + c];
        sum += v; sq = fmaf(v, v, sq);
    }
    __shared__ float sS[128], sQ[128];
    if (half) { sS[c] = sum; sQ[c] = sq; }
    __syncthreads();
    if (!half) {
        atomicAdd(&stats[c], sum + sS[c]);
        atomicAdd(&stats[128 + c], sq + sQ[c]);
    }
}

__global__ void bnfin_k(const float* __restrict__ stats, const float* __restrict__ gamma,
                        const float* __restrict__ beta, float* __restrict__ ss, float invN) {
    int c = threadIdx.x;   // 128 threads
    float mu  = stats[c] * invN;
    float var = fmaf(-mu, mu, stats[128 + c] * invN);
    float sc  = gamma[c] * rsqrtf(var + BN_EPS);
    ss[c]       = sc;
    ss[128 + c] = fmaf(-mu, sc, beta[c]);
}

// Fused BN-apply + residual + ReLU, elementwise float4, safe in-place.
__global__ __launch_bounds__(256) void apply_k(const float* H,
                                               const float* __restrict__ R,
                                               const float* __restrict__ ss,
                                               float* Xn, int n4) {
    int i = blockIdx.x * 256 + threadIdx.x;
    if (i >= n4) return;
    int c4 = (i & 31) << 2;
    float4 h = ((const float4*)H)[i];
    float4 r = ((const float4*)R)[i];
    float4 o;
    o.x = fmaxf(fmaf(h.x, ss[c4 + 0], ss[128 + c4 + 0]) + r.x, 0.f);
    o.y = fmaxf(fmaf(h.y, ss[c4 + 1], ss[128 + c4 + 1]) + r.y, 0.f);
    o.z = fmaxf(fmaf(h.z, ss[c4 + 2], ss[128 + c4 + 2]) + r.z, 0.f);
    o.w = fmaxf(fmaf(h.w, ss[c4 + 3], ss[128 + c4 + 3]) + r.w, 0.f);
    ((float4*)Xn)[i] = o;
}

// ---------------------------------------------------------------------------
extern "C" void kernel_launch(void* const* d_in, const int* in_sizes, int n_in,
                              void* d_out, int out_size, void* d_ws, size_t ws_size,
                              hipStream_t stream) {
    const float* x   = (const float*)d_in[0];
    const int*   src = (const int*)d_in[1];
    const int*   dst = (const int*)d_in[2];
    const float* W0  = (const float*)d_in[3];
    const float* b0  = (const float*)d_in[4];
    const float* W1  = (const float*)d_in[5];
    const float* b1  = (const float*)d_in[6];
    const float* W2  = (const float*)d_in[7];
    const float* b2  = (const float*)d_in[8];
    const float* g0  = (const float*)d_in[9];
    const float* be0 = (const float*)d_in[10];
    const float* g1  = (const float*)d_in[11];
    const float* be1 = (const float*)d_in[12];
    float* out = (float*)d_out;

    const int N = in_sizes[0] / 128;
    const int E = in_sizes[1];

    // workspace: bf16 M + 2 fp32 N x 128 buffers + Wt + offsets + stats
    char*  ws   = (char*)d_ws;
    size_t bufB = (size_t)N * 128 * sizeof(float);
    short* Mb = (short*)(ws);                 // N x 128 bf16 (fits in bufB)
    float* B  = (float*)(ws + bufB);
    float* Cb = (float*)(ws + 2 * bufB);
    size_t p  = 3 * bufB;
    int*   off = (int*)(ws + p);
    p += ((size_t)(N + 1) * sizeof(int) + 255) & ~(size_t)255;
    float* stats0 = (float*)(ws + p); p += 1024;
    float* stats1 = (float*)(ws + p); p += 1024;
    float* ss     = (float*)(ws + p); p += 1024;
    short* Wt0    = (short*)(ws + p); p += 128 * 128 * 2;
    short* Wt1    = (short*)(ws + p); p += 128 * 128 * 2;
    short* Wt2    = (short*)(ws + p); p += 128 * 64 * 2;

    const dim3 blk(256);
    const int gGemm  = (N + 127) / 128;
    const int gAgg   = (N + 3) / 4;
    const int gApply = (N * 32 + 255) / 256;
    const float invN = 1.f / (float)N;

    zero_k<<<2, blk, 0, stream>>>(stats0, 512);
    wtrans_k<<<64, blk, 0, stream>>>(W0, Wt0, 128, 128);
    wtrans_k<<<64, blk, 0, stream>>>(W1, Wt1, 128, 128);
    wtrans_k<<<32, blk, 0, stream>>>(W2, Wt2, 128, 64);
    build_off_k<<<(E + 256) / 256, blk, 0, stream>>>(dst, off, E, N);

    // ---- layer 0 ----
    mgemm_k<128><<<gGemm, blk, 0, stream>>>(x, Wt0, Mb, N);
    agg_k<128><<<gAgg, blk, 0, stream>>>(Mb, src, off, b0, B, N);
    stats_k<<<1024, blk, 0, stream>>>(B, stats0, N);
    bnfin_k<<<1, 128, 0, stream>>>(stats0, g0, be0, ss, invN);
    apply_k<<<gApply, blk, 0, stream>>>(B, x, ss, B, N * 32);

    // ---- layer 1 ----
    mgemm_k<128><<<gGemm, blk, 0, stream>>>(B, Wt1, Mb, N);
    agg_k<128><<<gAgg, blk, 0, stream>>>(Mb, src, off, b1, Cb, N);
    stats_k<<<1024, blk, 0, stream>>>(Cb, stats1, N);
    bnfin_k<<<1, 128, 0, stream>>>(stats1, g1, be1, ss, invN);
    apply_k<<<gApply, blk, 0, stream>>>(Cb, B, ss, Cb, N * 32);

    // ---- final conv ----
    mgemm_k<64><<<gGemm, blk, 0, stream>>>(Cb, Wt2, Mb, N);
    agg_k<64><<<gAgg, blk, 0, stream>>>(Mb, src, off, b2, out, N);
}